// Round 6
// baseline (82.069 us; speedup 1.0000x reference)
//
#include <hip/hip_runtime.h>

// Ball query (PointNet++ semantics), MI355X / gfx950.
// B=8, N=16384 points, M=1024 centroids, K=64 samples.
// One 64-lane wave per centroid. Each chunk = 256 points: lane l holds
// points base+4l..base+4l+3 via one float4 load per coordinate plane
// (3 loads/chunk instead of 12 scalar). Depth-1 software pipeline:
// chunk i+1's loads are issued before chunk i is classified, so the
// straggler waves (corner centroids scanning all 16384 points) pay
// max(L2 latency, VALU) per chunk instead of the sum.
//
// Ordered compaction (ascending point index = lane-major, then k):
//   nib[l]  = 4-bit hit mask for lane l's 4 points
//   m_k     = __ballot(nib bit k)            (wave-uniform SGPR masks)
//   slot    = count + sum_k popc(m_k & below(l)) + popc(nib & ((1<<k)-1))
// Early exit (wave-uniform) once count >= K.
//
// CLASSIFICATION ARITHMETIC (verified passing, round 4 — do not change):
//   cp  = fma(cz,pz, fma(cy,py, fl(cx*px)))   (K=3 dot, forward FMA chain)
//   p2,c2 = strict mul + sequential add (no FMA)
//   d2  = fl( fl(c2+p2) - 2*cp ),  r2 = 0.04f
// (fp32-strict / f64 variants both misclassify near-threshold points vs the
//  reference's matmul recompute — rounds 1-3 evidence.)

#define BQ_N 16384
#define BQ_M 1024
#define BQ_K 64
#define BQ_R2 0.04f

__global__ __launch_bounds__(256) void BallPointQuery_kernel(
    const float* __restrict__ pts,    // [B, 3, N]
    const float* __restrict__ cents,  // [B, 3, M]
    int* __restrict__ out)            // [B, M, K] int32
{
    const int N = BQ_N, M = BQ_M, K = BQ_K;
    const int lane = threadIdx.x & 63;
    const int cid  = (blockIdx.x << 2) + (threadIdx.x >> 6);  // wave id = centroid id
    const int b = cid >> 10;          // M = 1024
    const int m = cid & (M - 1);

    const float* p = pts   + (size_t)b * 3 * N;
    const float* c = cents + (size_t)b * 3 * M;
    const float cx = c[m];
    const float cy = c[M + m];
    const float cz = c[2 * M + m];

    // c2 = (cx*cx + cy*cy) + cz*cz, strict (no FMA).
    const float c2 = __fadd_rn(__fadd_rn(__fmul_rn(cx, cx), __fmul_rn(cy, cy)),
                               __fmul_rn(cz, cz));

    int* o = out + (size_t)cid * K;

    const float4* px4 = (const float4*)(p);          // planes are 64 KB apart,
    const float4* py4 = (const float4*)(p + N);      // 16B-aligned
    const float4* pz4 = (const float4*)(p + 2 * N);

    int count = 0;
    int first = 0;   // pad value; stays 0 if no neighbor found

    // Prefetch chunk 0 (256 points = 64 float4 per plane).
    float4 X = px4[lane], Y = py4[lane], Z = pz4[lane];

    for (int base = 0; base < N; base += 256) {
        // Issue next chunk's loads before touching this chunk's data.
        float4 Xn, Yn, Zn;
        const int nb = base + 256;
        if (nb < N) {                                 // wave-uniform
            const int q = (nb >> 2) + lane;
            Xn = px4[q]; Yn = py4[q]; Zn = pz4[q];
        }

        // Classify this lane's 4 points -> 4-bit nibble.
        const float xs[4] = {X.x, X.y, X.z, X.w};
        const float ys[4] = {Y.x, Y.y, Y.z, Y.w};
        const float zs[4] = {Z.x, Z.y, Z.z, Z.w};
        unsigned nib = 0;
        #pragma unroll
        for (int k = 0; k < 4; ++k) {
            const float p2 = __fadd_rn(
                __fadd_rn(__fmul_rn(xs[k], xs[k]), __fmul_rn(ys[k], ys[k])),
                __fmul_rn(zs[k], zs[k]));
            float cp = __fmul_rn(cx, xs[k]);
            cp = __fmaf_rn(cy, ys[k], cp);
            cp = __fmaf_rn(cz, zs[k], cp);
            const float d2 = __fsub_rn(__fadd_rn(c2, p2), __fmul_rn(2.0f, cp));
            nib |= (d2 <= BQ_R2 ? 1u : 0u) << k;
        }

        const unsigned long long m0 = __ballot((nib >> 0) & 1u);
        const unsigned long long m1 = __ballot((nib >> 1) & 1u);
        const unsigned long long m2 = __ballot((nib >> 2) & 1u);
        const unsigned long long m3 = __ballot((nib >> 3) & 1u);
        const unsigned long long any = m0 | m1 | m2 | m3;

        if (any) {                                    // wave-uniform
            if (count == 0) {
                const int l0 = __builtin_ctzll(any);  // lowest lane with a hit
                const unsigned n0 =
                      (unsigned)((m0 >> l0) & 1ull)
                    | ((unsigned)((m1 >> l0) & 1ull) << 1)
                    | ((unsigned)((m2 >> l0) & 1ull) << 2)
                    | ((unsigned)((m3 >> l0) & 1ull) << 3);
                first = base + 4 * l0 + __builtin_ctz(n0);
            }
            const unsigned long long below = (1ull << lane) - 1ull;
            int s = count + __popcll(m0 & below) + __popcll(m1 & below)
                          + __popcll(m2 & below) + __popcll(m3 & below);
            const int idx0 = base + 4 * lane;
            #pragma unroll
            for (int k = 0; k < 4; ++k) {
                if ((nib >> k) & 1u) {
                    if (s < K) o[s] = idx0 + k;
                    ++s;
                }
            }
            count += __popcll(m0) + __popcll(m1) + __popcll(m2) + __popcll(m3);
            if (count >= K) break;                    // wave-uniform early exit
        }

        X = Xn; Y = Yn; Z = Zn;   // last iter: dead assign of unread values
    }

    // Pad slots [min(count,K), K) with the first neighbor's index (or 0).
    const int cnt = count < K ? count : K;
    if (lane >= cnt) o[lane] = first;
}

extern "C" void kernel_launch(void* const* d_in, const int* in_sizes, int n_in,
                              void* d_out, int out_size, void* d_ws, size_t ws_size,
                              hipStream_t stream) {
    const float* pts   = (const float*)d_in[0];   // [8, 3, 16384] f32
    const float* cents = (const float*)d_in[1];   // [8, 3, 1024]  f32
    int* out = (int*)d_out;                       // [8, 1024, 64] int32

    // 8 * 1024 = 8192 centroids; 4 waves (centroids) per 256-thread block.
    BallPointQuery_kernel<<<8192 / 4, 256, 0, stream>>>(pts, cents, out);
}